// Round 1
// baseline (223.844 us; speedup 1.0000x reference)
//
#include <hip/hip_runtime.h>
#include <hip/hip_bf16.h>
#include <math.h>

#define WAVE 64

// ---------------- Kernel A: per-token softmax + top1/top2 ----------------
// One 64-lane wave per token (row of 64 logits). Lane e holds logit[s][e].
__global__ void router_softmax_top2(const float* __restrict__ x,
                                    int* __restrict__ top1,
                                    int* __restrict__ top2,
                                    float* __restrict__ w1,
                                    float* __restrict__ w2,
                                    int S) {
    const int wavesPerBlock = blockDim.x >> 6;
    const int wid  = threadIdx.x >> 6;
    const int lane = threadIdx.x & 63;
    const int s = blockIdx.x * wavesPerBlock + wid;
    if (s >= S) return;

    float v = x[(size_t)s * 64 + lane];

    // argmax with lowest-index tiebreak (matches jnp.argmax)
    float bv = v; int bi = lane;
    #pragma unroll
    for (int off = 32; off >= 1; off >>= 1) {
        float ov = __shfl_xor(bv, off, WAVE);
        int   oi = __shfl_xor(bi, off, WAVE);
        if (ov > bv || (ov == bv && oi < bi)) { bv = ov; bi = oi; }
    }
    const float m = bv;
    const int t1 = bi;

    // fp32 softmax
    float e = expf(v - m);
    float sum = e;
    #pragma unroll
    for (int off = 32; off >= 1; off >>= 1) sum += __shfl_xor(sum, off, WAVE);
    const float p = e / sum;

    // second argmax with top1 masked out
    float v2 = (lane == t1) ? -INFINITY : v;
    float bv2 = v2; int bi2 = lane;
    #pragma unroll
    for (int off = 32; off >= 1; off >>= 1) {
        float ov = __shfl_xor(bv2, off, WAVE);
        int   oi = __shfl_xor(bi2, off, WAVE);
        if (ov > bv2 || (ov == bv2 && oi < bi2)) { bv2 = ov; bi2 = oi; }
    }
    const int t2 = bi2;

    const float p1 = __shfl(p, t1, WAVE);
    const float p2 = __shfl(p, t2, WAVE);

    if (lane == 0) {
        top1[s] = t1; top2[s] = t2;
        w1[s] = p1;   w2[s] = p2;
    }
}

// ---------------- Kernel B1: per-chunk expert histograms ----------------
// One 64-lane block per 64-token chunk. Lane e counts tokens routed to expert e.
__global__ void chunk_hist(const int* __restrict__ top1,
                           const int* __restrict__ top2,
                           int* __restrict__ hist1,
                           int* __restrict__ hist2) {
    const int c = blockIdx.x;
    const int lane = threadIdx.x;
    const int t1 = top1[c * 64 + lane];
    const int t2 = top2[c * 64 + lane];
    int c1 = 0, c2 = 0;
    #pragma unroll 8
    for (int j = 0; j < 64; ++j) {
        c1 += (__shfl(t1, j, WAVE) == lane);
        c2 += (__shfl(t2, j, WAVE) == lane);
    }
    hist1[c * 64 + lane] = c1;
    hist2[c * 64 + lane] = c2;
}

// ---------------- Kernel B2: exclusive scan over chunks, per expert ----------------
// One 64-thread block; thread e scans its expert across all chunks.
__global__ void scan_hist(const int* __restrict__ hist1,
                          const int* __restrict__ hist2,
                          int* __restrict__ base1,
                          int* __restrict__ base2,
                          int* __restrict__ total1,
                          int nchunks) {
    const int e = threadIdx.x;
    int r1 = 0, r2 = 0;
    for (int c = 0; c < nchunks; ++c) {
        base1[c * 64 + e] = r1; r1 += hist1[c * 64 + e];
        base2[c * 64 + e] = r2; r2 += hist2[c * 64 + e];
    }
    total1[e] = r1;  // sum(mask1, axis=0): offset for rank2
}

// ---------------- Kernel B3: final ranks + scatter ----------------
// One 64-lane block per chunk. Within-chunk stable rank via shfl loop,
// then scatter combine weight + sec mask.
__global__ void rank_scatter(const int* __restrict__ top1,
                             const int* __restrict__ top2,
                             const float* __restrict__ w1,
                             const float* __restrict__ w2,
                             const int* __restrict__ base1,
                             const int* __restrict__ base2,
                             const int* __restrict__ total1,
                             float* __restrict__ out,
                             int S, int CAP) {
    const int c = blockIdx.x;
    const int i = threadIdx.x;
    const int s = c * 64 + i;
    const int t1 = top1[s];
    const int t2 = top2[s];

    int cnt1 = 0, cnt2 = 0;
    #pragma unroll 8
    for (int j = 0; j < 64; ++j) {
        const int o1 = __shfl(t1, j, WAVE);
        const int o2 = __shfl(t2, j, WAVE);
        cnt1 += (o1 == t1) && (j < i);
        cnt2 += (o2 == t2) && (j < i);
    }

    const int rank1 = base1[c * 64 + t1] + cnt1;
    const int rank2 = base2[c * 64 + t2] + cnt2 + total1[t2];

    const size_t secoff = (size_t)S * 64 * CAP;
    if (rank1 < CAP) {
        const size_t idx = ((size_t)s * 64 + t1) * CAP + rank1;
        out[idx] = w1[s];
        out[secoff + idx] = 1.0f;
    }
    if (rank2 < CAP) {
        const size_t idx = ((size_t)s * 64 + t2) * CAP + rank2;
        out[idx] = w2[s];
        out[secoff + idx] = 1.0f;
    }
}

extern "C" void kernel_launch(void* const* d_in, const int* in_sizes, int n_in,
                              void* d_out, int out_size, void* d_ws, size_t ws_size,
                              hipStream_t stream) {
    const float* x = (const float*)d_in[0];
    float* out = (float*)d_out;

    const int E = 64;
    const int S = in_sizes[0] / E;            // 8192
    // capacity: floor(2.0*S/E), round up to even, min 4
    int cap = (int)(2.0 * S / E);
    cap += cap % 2;
    if (cap < 4) cap = 4;

    const int nchunks = S / 64;               // 128

    // workspace layout (all 4-byte elements)
    char* w = (char*)d_ws;
    int*   top1   = (int*)w;                      w += (size_t)S * 4;
    int*   top2   = (int*)w;                      w += (size_t)S * 4;
    float* w1     = (float*)w;                    w += (size_t)S * 4;
    float* w2     = (float*)w;                    w += (size_t)S * 4;
    int*   hist1  = (int*)w;                      w += (size_t)nchunks * 64 * 4;
    int*   hist2  = (int*)w;                      w += (size_t)nchunks * 64 * 4;
    int*   base1  = (int*)w;                      w += (size_t)nchunks * 64 * 4;
    int*   base2  = (int*)w;                      w += (size_t)nchunks * 64 * 4;
    int*   total1 = (int*)w;                      w += 64 * 4;

    // 1) zero the (mostly-sparse) dense output: this is the roofline cost
    hipMemsetAsync(d_out, 0, (size_t)out_size * sizeof(float), stream);

    // 2) softmax + top2 (4 waves per 256-thread block)
    {
        const int wavesPerBlock = 4;
        const int blocks = (S + wavesPerBlock - 1) / wavesPerBlock;
        router_softmax_top2<<<blocks, wavesPerBlock * 64, 0, stream>>>(
            x, top1, top2, w1, w2, S);
    }

    // 3) per-chunk histograms
    chunk_hist<<<nchunks, 64, 0, stream>>>(top1, top2, hist1, hist2);

    // 4) exclusive scan across chunks
    scan_hist<<<1, 64, 0, stream>>>(hist1, hist2, base1, base2, total1, nchunks);

    // 5) ranks + scatter
    rank_scatter<<<nchunks, 64, 0, stream>>>(top1, top2, w1, w2,
                                             base1, base2, total1,
                                             out, S, cap);
}